// Round 11
// baseline (286.784 us; speedup 1.0000x reference)
//
#include <hip/hip_runtime.h>

#define D 64
#define ED 16

// ---------------------------------------------------------------------------
// Probe: is edge_index int64 or int32?  flag[0] = 1 -> int64, 0 -> int32.
// ---------------------------------------------------------------------------
__global__ void detect_idx64_kernel(const int* __restrict__ idx32, int* __restrict__ flag)
{
    __shared__ int any;
    if (threadIdx.x == 0) any = 0;
    __syncthreads();
    int v = 0;
    for (int i = threadIdx.x; i < 8192; i += blockDim.x)
        v |= idx32[2 * i + 1];
    if (v) atomicOr(&any, 1);
    __syncthreads();
    if (threadIdx.x == 0) flag[0] = (any == 0) ? 1 : 0;
}

__device__ __forceinline__ int load_idx(const void* p, size_t i, int is64)
{
    return is64 ? (int)((const long long*)p)[i] : ((const int*)p)[i];
}

// ---------------------------------------------------------------------------
// CSR build step 1: per-destination degree count (1 int atomic per edge).
// ---------------------------------------------------------------------------
__global__ void __launch_bounds__(256)
count_kernel(const void* __restrict__ edge_index, const int* __restrict__ flag,
             int* __restrict__ cnt, int n_edges)
{
    const int is64 = flag[0];
    const int stride = gridDim.x * blockDim.x;
    for (int e = blockIdx.x * blockDim.x + threadIdx.x; e < n_edges; e += stride) {
        int dst = load_idx(edge_index, (size_t)n_edges + e, is64);
        atomicAdd(&cnt[dst], 1);
    }
}

// ---------------------------------------------------------------------------
// CSR build step 2: two-level exclusive scan of cnt -> offs.
// ---------------------------------------------------------------------------
__global__ void scan1_kernel(const int* __restrict__ cnt, int* __restrict__ offs,
                             int* __restrict__ bsum, int n)
{
    __shared__ int sd[256];
    const int t = threadIdx.x;
    const int i = blockIdx.x * 256 + t;
    int v = (i < n) ? cnt[i] : 0;
    sd[t] = v;
    __syncthreads();
    for (int off = 1; off < 256; off <<= 1) {
        int add = (t >= off) ? sd[t - off] : 0;
        __syncthreads();
        sd[t] += add;
        __syncthreads();
    }
    if (i < n) offs[i] = sd[t] - v;          // exclusive
    if (t == 255) bsum[blockIdx.x] = sd[t];  // block total
}

__global__ void scan2_kernel(int* __restrict__ bsum, int nb)
{
    __shared__ int sd[512];
    const int t = threadIdx.x;
    int v = (t < nb) ? bsum[t] : 0;
    sd[t] = v;
    __syncthreads();
    for (int off = 1; off < 512; off <<= 1) {
        int add = (t >= off) ? sd[t - off] : 0;
        __syncthreads();
        sd[t] += add;
        __syncthreads();
    }
    if (t < nb) bsum[t] = sd[t] - v;         // exclusive block offsets
}

__global__ void scan3_kernel(int* __restrict__ offs, int* __restrict__ cursor,
                             const int* __restrict__ bsum, int n, int n_edges)
{
    const int i = blockIdx.x * 256 + threadIdx.x;
    if (i < n) {
        int v = offs[i] + bsum[i >> 8];
        offs[i]   = v;
        cursor[i] = v;
    }
    if (i == 0) offs[n] = n_edges;           // sentinel: deg = offs[i+1]-offs[i]
}

// ---------------------------------------------------------------------------
// CSR build step 3: scatter (src, eid) pairs to sorted-by-dst positions.
// ---------------------------------------------------------------------------
__global__ void __launch_bounds__(256)
scatter_kernel(const void* __restrict__ edge_index, const int* __restrict__ flag,
               int* __restrict__ cursor, int2* __restrict__ pair, int n_edges)
{
    const int is64 = flag[0];
    const int stride = gridDim.x * blockDim.x;
    for (int e = blockIdx.x * blockDim.x + threadIdx.x; e < n_edges; e += stride) {
        int src = load_idx(edge_index, e, is64);
        int dst = load_idx(edge_index, (size_t)n_edges + e, is64);
        int pos = atomicAdd(&cursor[dst], 1);
        pair[pos] = make_int2(src, e);
    }
}

// ---------------------------------------------------------------------------
// Gather-reduce, 4-SLOT MLP version (round-11).  Rounds 7/9/10 proved the
// kernel is invariant to bytes/lines/occupancy/prologue -> it is dependent-
// latency bound (offs -> pair -> gathers = ~2.5 serialized round-trips per
// node, nodes sequential per wave).  Fix: process 4 nodes per wave
// CONCURRENTLY — issue all 8 offs, 4 pair, 64 x-row and 16 ea gathers before
// any accumulation wait -> ~0.75 rounds/node.  Static indexing via per-slot
// macros (no runtime-indexed arrays -> no scratch).  deg>16 tails (~2.7% of
// nodes) fall into the old serial loop per slot.
//   agg_mean[i] = ( sum_e x[src_e] + (sum_e ea[e]) @ W_e + deg*b_e ) / max(deg,1)
// ---------------------------------------------------------------------------
#define GATHER_X(J)                                                         \
    _Pragma("unroll")                                                       \
    for (int m = 0; m < 16; ++m) {                                          \
        int s = __shfl(p##J.x, m);                                          \
        t##J[m] = (m < nb##J) ? x[(size_t)s * D + lane] : 0.0f;             \
    }

#define GATHER_EA(J)                                                        \
    _Pragma("unroll")                                                       \
    for (int mm = 0; mm < 4; ++mm) {                                        \
        int m = sub + 4 * mm;                                               \
        int eid = __shfl(p##J.y, m);                                        \
        if (m < nb##J) eac##J += edge_attr[(size_t)eid * ED + k16];         \
    }

#define FINISH(J) do {                                                      \
    float xs = 0.0f;                                                        \
    _Pragma("unroll")                                                       \
    for (int m = 0; m < 16; ++m) xs += t##J[m];                             \
    for (int j0 = 16; j0 < deg##J; j0 += 16) {      /* rare tail */         \
        const int nbt = min(16, deg##J - j0);                               \
        int2 pt = make_int2(0, 0);                                          \
        if (lane < nbt) pt = pair[beg##J + j0 + lane];                      \
        float tt[16];                                                       \
        _Pragma("unroll")                                                   \
        for (int m = 0; m < 16; ++m) {                                      \
            int s = __shfl(pt.x, m);                                        \
            tt[m] = (m < nbt) ? x[(size_t)s * D + lane] : 0.0f;             \
        }                                                                   \
        _Pragma("unroll")                                                   \
        for (int mm = 0; mm < 4; ++mm) {                                    \
            int m = sub + 4 * mm;                                           \
            int eid = __shfl(pt.y, m);                                      \
            if (m < nbt) eac##J += edge_attr[(size_t)eid * ED + k16];       \
        }                                                                   \
        _Pragma("unroll")                                                   \
        for (int m = 0; m < 16; ++m) xs += tt[m];                           \
    }                                                                       \
    float eaf = eac##J + __shfl_xor(eac##J, 16);                            \
    eaf += __shfl_xor(eaf, 32);                                             \
    float acc = xs + (float)deg##J * beL;                                   \
    _Pragma("unroll")                                                       \
    for (int k = 0; k < ED; ++k) acc += __shfl(eaf, k) * Wreg[k];           \
    if (v##J)                                                               \
        agg[(size_t)n##J * D + lane] = acc * (1.0f / fmaxf((float)deg##J, 1.0f)); \
} while (0)

__global__ void
reduce_kernel(const float* __restrict__ x,
              const float* __restrict__ edge_attr,
              const float* __restrict__ W_e,
              const float* __restrict__ b_e,
              const int2* __restrict__ pair,
              const int* __restrict__ offs,   // n_nodes+1 (sentinel)
              float* __restrict__ agg,
              int n_nodes)
{
    const int lane = threadIdx.x & 63;
    const int wid  = threadIdx.x >> 6;
    const int sub  = lane >> 4;
    const int k16  = lane & 15;

    // per-lane register copy of W_e[:,lane] and b_e[lane]
    float Wreg[ED];
    #pragma unroll
    for (int k = 0; k < ED; ++k) Wreg[k] = W_e[k * D + lane];
    const float beL = b_e[lane];

    const int tw = gridDim.x * 4;            // total waves
    const int wg = blockIdx.x * 4 + wid;     // this wave's id

    for (int k0 = 0; wg + k0 * tw < n_nodes; k0 += 4) {
        const int  n0 = wg + (k0 + 0) * tw;
        const int  n1 = wg + (k0 + 1) * tw;
        const int  n2 = wg + (k0 + 2) * tw;
        const int  n3 = wg + (k0 + 3) * tw;
        const bool v0 = true;
        const bool v1 = n1 < n_nodes;
        const bool v2 = n2 < n_nodes;
        const bool v3 = n3 < n_nodes;
        const int  c1 = v1 ? n1 : 0;
        const int  c2 = v2 ? n2 : 0;
        const int  c3 = v3 ? n3 : 0;

        // --- round 1: 8 independent offs loads ---
        const int beg0 = offs[n0], end0 = offs[n0 + 1];
        const int beg1 = offs[c1], end1 = offs[c1 + 1];
        const int beg2 = offs[c2], end2 = offs[c2 + 1];
        const int beg3 = offs[c3], end3 = offs[c3 + 1];
        const int deg0 = end0 - beg0;
        const int deg1 = v1 ? (end1 - beg1) : 0;
        const int deg2 = v2 ? (end2 - beg2) : 0;
        const int deg3 = v3 ? (end3 - beg3) : 0;
        const int nb0 = min(deg0, 16);
        const int nb1 = min(deg1, 16);
        const int nb2 = min(deg2, 16);
        const int nb3 = min(deg3, 16);

        // --- round 2: 4 independent pair loads ---
        int2 p0 = make_int2(0, 0); if (lane < nb0) p0 = pair[beg0 + lane];
        int2 p1 = make_int2(0, 0); if (lane < nb1) p1 = pair[beg1 + lane];
        int2 p2 = make_int2(0, 0); if (lane < nb2) p2 = pair[beg2 + lane];
        int2 p3 = make_int2(0, 0); if (lane < nb3) p3 = pair[beg3 + lane];

        // --- round 3: ALL gathers issued before any accumulation ---
        float t0[16], t1[16], t2[16], t3[16];
        float eac0 = 0.0f, eac1 = 0.0f, eac2 = 0.0f, eac3 = 0.0f;
        GATHER_X(0); GATHER_X(1); GATHER_X(2); GATHER_X(3);
        GATHER_EA(0); GATHER_EA(1); GATHER_EA(2); GATHER_EA(3);

        // --- accumulate / tails / epilogue / store ---
        FINISH(0); FINISH(1); FINISH(2); FINISH(3);
    }
}

// ---------------------------------------------------------------------------
// Fallback edge phase (atomic scatter) — used only if ws_size is too small.
// ---------------------------------------------------------------------------
__global__ void __launch_bounds__(256)
edge_scatter_kernel(const float* __restrict__ x,
                    const float* __restrict__ edge_attr,
                    const float* __restrict__ W_e,
                    const float* __restrict__ b_e,
                    const void* __restrict__ edge_index,
                    const int* __restrict__ flag,
                    float* __restrict__ agg,
                    float* __restrict__ cnt,
                    int n_edges)
{
    __shared__ float We[ED * D];
    __shared__ float be[D];
    for (int i = threadIdx.x; i < ED * D; i += blockDim.x) We[i] = W_e[i];
    if (threadIdx.x < D) be[threadIdx.x] = b_e[threadIdx.x];
    __syncthreads();

    const int is64 = flag[0];
    const int lane = threadIdx.x & 63;
    const int wid  = threadIdx.x >> 6;
    const int estr = gridDim.x * 4;

    for (int e = blockIdx.x * 4 + wid; e < n_edges; e += estr) {
        int src = load_idx(edge_index, e, is64);
        int dst = load_idx(edge_index, (size_t)n_edges + e, is64);
        const float4* ea = (const float4*)(edge_attr + (size_t)e * ED);
        float4 e0 = ea[0], e1 = ea[1], e2 = ea[2], e3 = ea[3];

        float m = be[lane] + x[(size_t)src * D + lane];
        m += e0.x * We[ 0*D + lane] + e0.y * We[ 1*D + lane]
           + e0.z * We[ 2*D + lane] + e0.w * We[ 3*D + lane];
        m += e1.x * We[ 4*D + lane] + e1.y * We[ 5*D + lane]
           + e1.z * We[ 6*D + lane] + e1.w * We[ 7*D + lane];
        m += e2.x * We[ 8*D + lane] + e2.y * We[ 9*D + lane]
           + e2.z * We[10*D + lane] + e2.w * We[11*D + lane];
        m += e3.x * We[12*D + lane] + e3.y * We[13*D + lane]
           + e3.z * We[14*D + lane] + e3.w * We[15*D + lane];

        atomicAdd(&agg[(size_t)dst * D + lane], m);
        if (lane == 0) atomicAdd(&cnt[dst], 1.0f);
    }
}

__global__ void divide_kernel(float* __restrict__ agg, const float* __restrict__ cnt, int n_nodes)
{
    const int i = blockIdx.x * 256 + threadIdx.x;
    if (i < n_nodes * D) {
        float c = cnt[i >> 6];
        agg[i] *= 1.0f / fmaxf(c, 1.0f);
    }
}

// ---------------------------------------------------------------------------
// Node phase as one GEMM:  out = [agg | x] @ [W_l ; W_r] + b_l
// (register discipline per round-5 lesson: rolled s-loop, unroll 4 kk-loop,
//  __launch_bounds__(256,4) caps VGPR at 128.)  UNCHANGED this round.
// ---------------------------------------------------------------------------
#define BM 128
#define BK 32
#define ATP 132   // padded row length (dwords): 132*4B % 16B == 0

__global__ void __launch_bounds__(256, 4)
node_gemm_kernel(const float* x,
                 const float* agg,                // == out (in-place)
                 const float* __restrict__ W_l,
                 const float* __restrict__ b_l,
                 const float* __restrict__ W_r,
                 float* out,
                 int n_nodes)
{
    __shared__ float AT[BK][ATP];     // 16.5 KB
    __shared__ float Wt[BK][D];       // 8 KB

    const int t   = threadIdx.x;
    const int to  = t & 15;           // col group: cols 4*to .. 4*to+3
    const int tm  = t >> 4;           // node group: nodes 8*tm .. 8*tm+7
    const int base = blockIdx.x * BM;

    float acc[8][4];
    #pragma unroll
    for (int n = 0; n < 8; ++n)
        #pragma unroll
        for (int c = 0; c < 4; ++c) acc[n][c] = 0.0f;

    #pragma unroll 1
    for (int s = 0; s < 4; ++s) {
        const float* src  = (s < 2) ? agg : x;
        const float* Wsrc = (s < 2) ? W_l : W_r;
        const int    k0   = (s & 1) * BK;

        __syncthreads();   // previous step's LDS reads done before overwrite

        // stage A^T: 128 nodes x 32 k  (4 float4 loads / thread)
        #pragma unroll
        for (int q = 0; q < 4; ++q) {
            const int idx  = t + 256 * q;       // 0..1023
            const int node = idx >> 3;          // 0..127
            const int kq   = (idx & 7) * 4;     // 0,4,..,28
            float4 v = make_float4(0.f, 0.f, 0.f, 0.f);
            if (base + node < n_nodes)
                v = *(const float4*)(src + (size_t)(base + node) * D + k0 + kq);
            AT[kq + 0][node] = v.x;
            AT[kq + 1][node] = v.y;
            AT[kq + 2][node] = v.z;
            AT[kq + 3][node] = v.w;
        }
        // stage W: 32 rows x 64 cols  (2 float4 loads / thread)
        #pragma unroll
        for (int q = 0; q < 2; ++q) {
            const int idx = t + 256 * q;        // 0..511
            const int kk  = idx >> 4;           // 0..31
            const int cq  = (idx & 15) * 4;
            *(float4*)&Wt[kk][cq] = *(const float4*)(Wsrc + (size_t)(k0 + kk) * D + cq);
        }
        __syncthreads();

        #pragma unroll 4
        for (int kk = 0; kk < BK; ++kk) {
            float4 a0 = *(const float4*)&AT[kk][tm * 8];
            float4 a1 = *(const float4*)&AT[kk][tm * 8 + 4];
            float4 w  = *(const float4*)&Wt[kk][to * 4];
            acc[0][0] += a0.x * w.x; acc[0][1] += a0.x * w.y; acc[0][2] += a0.x * w.z; acc[0][3] += a0.x * w.w;
            acc[1][0] += a0.y * w.x; acc[1][1] += a0.y * w.y; acc[1][2] += a0.y * w.z; acc[1][3] += a0.y * w.w;
            acc[2][0] += a0.z * w.x; acc[2][1] += a0.z * w.y; acc[2][2] += a0.z * w.z; acc[2][3] += a0.z * w.w;
            acc[3][0] += a0.w * w.x; acc[3][1] += a0.w * w.y; acc[3][2] += a0.w * w.z; acc[3][3] += a0.w * w.w;
            acc[4][0] += a1.x * w.x; acc[4][1] += a1.x * w.y; acc[4][2] += a1.x * w.z; acc[4][3] += a1.x * w.w;
            acc[5][0] += a1.y * w.x; acc[5][1] += a1.y * w.y; acc[5][2] += a1.y * w.z; acc[5][3] += a1.y * w.w;
            acc[6][0] += a1.z * w.x; acc[6][1] += a1.z * w.y; acc[6][2] += a1.z * w.z; acc[6][3] += a1.z * w.w;
            acc[7][0] += a1.w * w.x; acc[7][1] += a1.w * w.y; acc[7][2] += a1.w * w.z; acc[7][3] += a1.w * w.w;
        }
    }

    // epilogue: add bias, store (coalesced float4; reads of agg all done)
    const float4 bb = *(const float4*)(b_l + to * 4);
    #pragma unroll
    for (int n = 0; n < 8; ++n) {
        const int node = base + tm * 8 + n;
        if (node < n_nodes) {
            float4 r = make_float4(acc[n][0] + bb.x, acc[n][1] + bb.y,
                                   acc[n][2] + bb.z, acc[n][3] + bb.w);
            *(float4*)(out + (size_t)node * D + to * 4) = r;
        }
    }
}

// ---------------------------------------------------------------------------
extern "C" void kernel_launch(void* const* d_in, const int* in_sizes, int n_in,
                              void* d_out, int out_size, void* d_ws, size_t ws_size,
                              hipStream_t stream)
{
    const float* x         = (const float*)d_in[0];
    const float* edge_attr = (const float*)d_in[1];
    const float* W_e       = (const float*)d_in[2];
    const float* b_e       = (const float*)d_in[3];
    const float* W_l       = (const float*)d_in[4];
    const float* b_l       = (const float*)d_in[5];
    const float* W_r       = (const float*)d_in[6];
    const void*  edge_index= d_in[7];

    const int n_nodes = in_sizes[0] / D;
    const int n_edges = in_sizes[1] / ED;

    float* out = (float*)d_out;

    // workspace layout (bytes); offs gets n+1 entries (sentinel)
    const size_t n_align = ((size_t)n_nodes + 255) & ~(size_t)255;
    const int    NB      = (n_nodes + 255) / 256;       // scan blocks
    const size_t o_flag  = 0;
    const size_t o_cnt   = 512;
    const size_t o_offs  = o_cnt  + n_align * 4;
    const size_t o_cur   = o_offs + n_align * 4 + 256;  // +256: sentinel room
    const size_t o_bsum  = o_cur  + n_align * 4;
    const size_t o_pair  = (o_bsum + (size_t)NB * 4 + 255) & ~(size_t)255;
    const size_t need    = o_pair + (size_t)n_edges * 8;

    int* flag = (int*)((char*)d_ws + o_flag);

    detect_idx64_kernel<<<1, 256, 0, stream>>>((const int*)edge_index, flag);

    if (need <= ws_size && NB <= 512) {
        int*  cnt    = (int*)((char*)d_ws + o_cnt);
        int*  offs   = (int*)((char*)d_ws + o_offs);
        int*  cursor = (int*)((char*)d_ws + o_cur);
        int*  bsum   = (int*)((char*)d_ws + o_bsum);
        int2* pair   = (int2*)((char*)d_ws + o_pair);

        hipMemsetAsync(cnt, 0, n_align * 4, stream);

        count_kernel<<<2048, 256, 0, stream>>>(edge_index, flag, cnt, n_edges);
        scan1_kernel<<<NB, 256, 0, stream>>>(cnt, offs, bsum, n_nodes);
        scan2_kernel<<<1, 512, 0, stream>>>(bsum, NB);
        scan3_kernel<<<NB, 256, 0, stream>>>(offs, cursor, bsum, n_nodes, n_edges);
        scatter_kernel<<<2048, 256, 0, stream>>>(edge_index, flag, cursor, pair, n_edges);
        reduce_kernel<<<2048, 256, 0, stream>>>(
            x, edge_attr, W_e, b_e, pair, offs, out, n_nodes);
    } else {
        // fallback: atomic scatter path
        float* cntf = (float*)((char*)d_ws + o_cnt);
        hipMemsetAsync(out, 0, (size_t)out_size * sizeof(float), stream);
        hipMemsetAsync(cntf, 0, (size_t)n_nodes * sizeof(float), stream);
        edge_scatter_kernel<<<4096, 256, 0, stream>>>(
            x, edge_attr, W_e, b_e, edge_index, flag, out, cntf, n_edges);
        divide_kernel<<<(n_nodes * D + 255) / 256, 256, 0, stream>>>(out, cntf, n_nodes);
    }

    node_gemm_kernel<<<(n_nodes + BM - 1) / BM, 256, 0, stream>>>(
        x, out, W_l, b_l, W_r, out, n_nodes);
}

// Round 12
// 254.329 us; speedup vs baseline: 1.1276x; 1.1276x over previous
//
#include <hip/hip_runtime.h>

#define D 64
#define ED 16

// ---------------------------------------------------------------------------
// Inline int64/int32 probe: sample 64 odd dwords; int64 (nonneg, <2^31) ->
// all high words zero.  For int32 data these are 64 random indices — P(all
// zero) ~ 1e-320.  Wave-uniform via __all; no separate kernel, no flag slot.
// ---------------------------------------------------------------------------
__device__ __forceinline__ int detect_is64(const int* __restrict__ idx32)
{
    int v = idx32[2 * (threadIdx.x & 63) + 1];
    return __all(v == 0) ? 1 : 0;
}

__device__ __forceinline__ int load_idx(const void* p, size_t i, int is64)
{
    return is64 ? (int)((const long long*)p)[i] : ((const int*)p)[i];
}

// ---------------------------------------------------------------------------
// CSR build step 1: per-destination degree count (1 int atomic per edge).
// ---------------------------------------------------------------------------
__global__ void __launch_bounds__(256)
count_kernel(const void* __restrict__ edge_index, int* __restrict__ cnt, int n_edges)
{
    const int is64 = detect_is64((const int*)edge_index);
    const int stride = gridDim.x * blockDim.x;
    for (int e = blockIdx.x * blockDim.x + threadIdx.x; e < n_edges; e += stride) {
        int dst = load_idx(edge_index, (size_t)n_edges + e, is64);
        atomicAdd(&cnt[dst], 1);
    }
}

// ---------------------------------------------------------------------------
// CSR build step 2a: per-256-block exclusive scan; bsum = block totals.
// ---------------------------------------------------------------------------
__global__ void scan1_kernel(const int* __restrict__ cnt, int* __restrict__ offs,
                             int* __restrict__ bsum, int n)
{
    __shared__ int sd[256];
    const int t = threadIdx.x;
    const int i = blockIdx.x * 256 + t;
    int v = (i < n) ? cnt[i] : 0;
    sd[t] = v;
    __syncthreads();
    for (int off = 1; off < 256; off <<= 1) {
        int add = (t >= off) ? sd[t - off] : 0;
        __syncthreads();
        sd[t] += add;
        __syncthreads();
    }
    if (i < n) offs[i] = sd[t] - v;          // exclusive within block
    if (t == 255) bsum[blockIdx.x] = sd[t];  // block total
}

// ---------------------------------------------------------------------------
// CSR build step 2b (absorbs old scan2): each block reduces its own bsum
// prefix (<=512 ints from L2 — trivial), adds it, writes offs+cursor,
// appends sentinel.
// ---------------------------------------------------------------------------
__global__ void scan3_kernel(int* __restrict__ offs, int* __restrict__ cursor,
                             const int* __restrict__ bsum, int n, int n_edges)
{
    __shared__ int red[256];
    int part = 0;
    for (int j = threadIdx.x; j < blockIdx.x; j += 256) part += bsum[j];
    red[threadIdx.x] = part;
    __syncthreads();
    for (int off = 128; off > 0; off >>= 1) {
        if (threadIdx.x < off) red[threadIdx.x] += red[threadIdx.x + off];
        __syncthreads();
    }
    const int S = red[0];
    const int i = blockIdx.x * 256 + threadIdx.x;
    if (i < n) {
        int v = offs[i] + S;
        offs[i]   = v;
        cursor[i] = v;
    }
    if (i == 0) offs[n] = n_edges;           // sentinel: deg = offs[i+1]-offs[i]
}

// ---------------------------------------------------------------------------
// CSR build step 3: scatter (src, eid) pairs to sorted-by-dst positions.
// ---------------------------------------------------------------------------
__global__ void __launch_bounds__(256)
scatter_kernel(const void* __restrict__ edge_index,
               int* __restrict__ cursor, int2* __restrict__ pair, int n_edges)
{
    const int is64 = detect_is64((const int*)edge_index);
    const int stride = gridDim.x * blockDim.x;
    for (int e = blockIdx.x * blockDim.x + threadIdx.x; e < n_edges; e += stride) {
        int src = load_idx(edge_index, e, is64);
        int dst = load_idx(edge_index, (size_t)n_edges + e, is64);
        int pos = atomicAdd(&cursor[dst], 1);
        pair[pos] = make_int2(src, e);
    }
}

// ---------------------------------------------------------------------------
// Gather-reduce, 2-SLOT MLP (round-12).  Round-11's 4-slot spilled (compiler
// clamped VGPR=64, t-arrays to scratch, WRITE 25->82 MB, 160 us) — the
// chain-depth theory was never tested.  2 slots = 32 t-regs + 16 W + addr
// ~= 100 VGPR, pinned with __launch_bounds__(256,2) (cap 128, no clamp, no
// spill).  Wave handles contiguous node pair {2w, 2w+1}: shared offs line,
// adjacent pair segments; all offs/pair/gather loads for BOTH nodes issued
// before any accumulation wait -> rounds/node ~2.5 -> ~1.4.
//   agg_mean[i] = ( sum_e x[src_e] + (sum_e ea[e]) @ W_e + deg*b_e ) / max(deg,1)
// ---------------------------------------------------------------------------
#define GATHER_X(J)                                                         \
    _Pragma("unroll")                                                       \
    for (int m = 0; m < 16; ++m) {                                          \
        int s = __shfl(p##J.x, m);                                          \
        t##J[m] = (m < nb##J) ? x[(size_t)s * D + lane] : 0.0f;             \
    }

#define GATHER_EA(J)                                                        \
    _Pragma("unroll")                                                       \
    for (int mm = 0; mm < 4; ++mm) {                                        \
        int m = sub + 4 * mm;                                               \
        int eid = __shfl(p##J.y, m);                                        \
        if (m < nb##J) eac##J += edge_attr[(size_t)eid * ED + k16];         \
    }

#define FINISH(J) do {                                                      \
    float xs = 0.0f;                                                        \
    _Pragma("unroll")                                                       \
    for (int m = 0; m < 16; ++m) xs += t##J[m];                             \
    for (int j0 = 16; j0 < deg##J; j0 += 16) {      /* rare tail (~2.7%) */ \
        const int nbt = min(16, deg##J - j0);                               \
        int2 pt = make_int2(0, 0);                                          \
        if (lane < nbt) pt = pair[beg##J + j0 + lane];                      \
        float tt[16];                                                       \
        _Pragma("unroll")                                                   \
        for (int m = 0; m < 16; ++m) {                                      \
            int s = __shfl(pt.x, m);                                        \
            tt[m] = (m < nbt) ? x[(size_t)s * D + lane] : 0.0f;             \
        }                                                                   \
        _Pragma("unroll")                                                   \
        for (int mm = 0; mm < 4; ++mm) {                                    \
            int m = sub + 4 * mm;                                           \
            int eid = __shfl(pt.y, m);                                      \
            if (m < nbt) eac##J += edge_attr[(size_t)eid * ED + k16];       \
        }                                                                   \
        _Pragma("unroll")                                                   \
        for (int m = 0; m < 16; ++m) xs += tt[m];                           \
    }                                                                       \
    float eaf = eac##J + __shfl_xor(eac##J, 16);                            \
    eaf += __shfl_xor(eaf, 32);                                             \
    float acc = xs + (float)deg##J * beL;                                   \
    _Pragma("unroll")                                                       \
    for (int k = 0; k < ED; ++k) acc += __shfl(eaf, k) * Wreg[k];           \
    if (v##J)                                                               \
        agg[(size_t)n##J * D + lane] = acc * (1.0f / fmaxf((float)deg##J, 1.0f)); \
} while (0)

__global__ void __launch_bounds__(256, 2)
reduce_kernel(const float* __restrict__ x,
              const float* __restrict__ edge_attr,
              const float* __restrict__ W_e,
              const float* __restrict__ b_e,
              const int2* __restrict__ pair,
              const int* __restrict__ offs,   // n_nodes+1 (sentinel)
              float* __restrict__ agg,
              int n_nodes)
{
    const int lane = threadIdx.x & 63;
    const int wid  = threadIdx.x >> 6;
    const int sub  = lane >> 4;
    const int k16  = lane & 15;

    // per-lane register copy of W_e[:,lane] and b_e[lane]
    float Wreg[ED];
    #pragma unroll
    for (int k = 0; k < ED; ++k) Wreg[k] = W_e[k * D + lane];
    const float beL = b_e[lane];

    const int tw = gridDim.x * 4;            // total waves
    const int wg = blockIdx.x * 4 + wid;     // this wave's id

    for (int base = wg * 2; base < n_nodes; base += tw * 2) {
        const int  n0 = base;
        const int  n1 = base + 1;
        const bool v0 = true;
        const bool v1 = n1 < n_nodes;
        const int  c1 = v1 ? n1 : n0;

        // --- round 1: offs loads for both nodes (contiguous, scalar-able) ---
        const int beg0 = offs[n0];
        const int mid  = offs[n0 + 1];
        const int beg1 = offs[c1];
        const int end1 = offs[c1 + 1];
        const int deg0 = mid - beg0;
        const int deg1 = v1 ? (end1 - beg1) : 0;
        const int nb0 = min(deg0, 16);
        const int nb1 = min(deg1, 16);

        // --- round 2: both pair loads ---
        int2 p0 = make_int2(0, 0); if (lane < nb0) p0 = pair[beg0 + lane];
        int2 p1 = make_int2(0, 0); if (lane < nb1) p1 = pair[beg1 + lane];

        // --- round 3: ALL gathers for both nodes before any wait ---
        float t0[16], t1[16];
        float eac0 = 0.0f, eac1 = 0.0f;
        GATHER_X(0); GATHER_X(1);
        GATHER_EA(0); GATHER_EA(1);

        // --- accumulate / tails / epilogue / store ---
        FINISH(0); FINISH(1);
    }
}

// ---------------------------------------------------------------------------
// Fallback edge phase (atomic scatter) — used only if ws_size is too small.
// ---------------------------------------------------------------------------
__global__ void __launch_bounds__(256)
edge_scatter_kernel(const float* __restrict__ x,
                    const float* __restrict__ edge_attr,
                    const float* __restrict__ W_e,
                    const float* __restrict__ b_e,
                    const void* __restrict__ edge_index,
                    float* __restrict__ agg,
                    float* __restrict__ cnt,
                    int n_edges)
{
    __shared__ float We[ED * D];
    __shared__ float be[D];
    for (int i = threadIdx.x; i < ED * D; i += blockDim.x) We[i] = W_e[i];
    if (threadIdx.x < D) be[threadIdx.x] = b_e[threadIdx.x];
    __syncthreads();

    const int is64 = detect_is64((const int*)edge_index);
    const int lane = threadIdx.x & 63;
    const int wid  = threadIdx.x >> 6;
    const int estr = gridDim.x * 4;

    for (int e = blockIdx.x * 4 + wid; e < n_edges; e += estr) {
        int src = load_idx(edge_index, e, is64);
        int dst = load_idx(edge_index, (size_t)n_edges + e, is64);
        const float4* ea = (const float4*)(edge_attr + (size_t)e * ED);
        float4 e0 = ea[0], e1 = ea[1], e2 = ea[2], e3 = ea[3];

        float m = be[lane] + x[(size_t)src * D + lane];
        m += e0.x * We[ 0*D + lane] + e0.y * We[ 1*D + lane]
           + e0.z * We[ 2*D + lane] + e0.w * We[ 3*D + lane];
        m += e1.x * We[ 4*D + lane] + e1.y * We[ 5*D + lane]
           + e1.z * We[ 6*D + lane] + e1.w * We[ 7*D + lane];
        m += e2.x * We[ 8*D + lane] + e2.y * We[ 9*D + lane]
           + e2.z * We[10*D + lane] + e2.w * We[11*D + lane];
        m += e3.x * We[12*D + lane] + e3.y * We[13*D + lane]
           + e3.z * We[14*D + lane] + e3.w * We[15*D + lane];

        atomicAdd(&agg[(size_t)dst * D + lane], m);
        if (lane == 0) atomicAdd(&cnt[dst], 1.0f);
    }
}

__global__ void divide_kernel(float* __restrict__ agg, const float* __restrict__ cnt, int n_nodes)
{
    const int i = blockIdx.x * 256 + threadIdx.x;
    if (i < n_nodes * D) {
        float c = cnt[i >> 6];
        agg[i] *= 1.0f / fmaxf(c, 1.0f);
    }
}

// ---------------------------------------------------------------------------
// Node phase as one GEMM:  out = [agg | x] @ [W_l ; W_r] + b_l
// (register discipline per round-5 lesson: rolled s-loop, unroll 4 kk-loop,
//  __launch_bounds__(256,4) caps VGPR at 128.)  UNCHANGED.
// ---------------------------------------------------------------------------
#define BM 128
#define BK 32
#define ATP 132   // padded row length (dwords): 132*4B % 16B == 0

__global__ void __launch_bounds__(256, 4)
node_gemm_kernel(const float* x,
                 const float* agg,                // == out (in-place)
                 const float* __restrict__ W_l,
                 const float* __restrict__ b_l,
                 const float* __restrict__ W_r,
                 float* out,
                 int n_nodes)
{
    __shared__ float AT[BK][ATP];     // 16.5 KB
    __shared__ float Wt[BK][D];       // 8 KB

    const int t   = threadIdx.x;
    const int to  = t & 15;           // col group: cols 4*to .. 4*to+3
    const int tm  = t >> 4;           // node group: nodes 8*tm .. 8*tm+7
    const int base = blockIdx.x * BM;

    float acc[8][4];
    #pragma unroll
    for (int n = 0; n < 8; ++n)
        #pragma unroll
        for (int c = 0; c < 4; ++c) acc[n][c] = 0.0f;

    #pragma unroll 1
    for (int s = 0; s < 4; ++s) {
        const float* src  = (s < 2) ? agg : x;
        const float* Wsrc = (s < 2) ? W_l : W_r;
        const int    k0   = (s & 1) * BK;

        __syncthreads();   // previous step's LDS reads done before overwrite

        // stage A^T: 128 nodes x 32 k  (4 float4 loads / thread)
        #pragma unroll
        for (int q = 0; q < 4; ++q) {
            const int idx  = t + 256 * q;       // 0..1023
            const int node = idx >> 3;          // 0..127
            const int kq   = (idx & 7) * 4;     // 0,4,..,28
            float4 v = make_float4(0.f, 0.f, 0.f, 0.f);
            if (base + node < n_nodes)
                v = *(const float4*)(src + (size_t)(base + node) * D + k0 + kq);
            AT[kq + 0][node] = v.x;
            AT[kq + 1][node] = v.y;
            AT[kq + 2][node] = v.z;
            AT[kq + 3][node] = v.w;
        }
        // stage W: 32 rows x 64 cols  (2 float4 loads / thread)
        #pragma unroll
        for (int q = 0; q < 2; ++q) {
            const int idx = t + 256 * q;        // 0..511
            const int kk  = idx >> 4;           // 0..31
            const int cq  = (idx & 15) * 4;
            *(float4*)&Wt[kk][cq] = *(const float4*)(Wsrc + (size_t)(k0 + kk) * D + cq);
        }
        __syncthreads();

        #pragma unroll 4
        for (int kk = 0; kk < BK; ++kk) {
            float4 a0 = *(const float4*)&AT[kk][tm * 8];
            float4 a1 = *(const float4*)&AT[kk][tm * 8 + 4];
            float4 w  = *(const float4*)&Wt[kk][to * 4];
            acc[0][0] += a0.x * w.x; acc[0][1] += a0.x * w.y; acc[0][2] += a0.x * w.z; acc[0][3] += a0.x * w.w;
            acc[1][0] += a0.y * w.x; acc[1][1] += a0.y * w.y; acc[1][2] += a0.y * w.z; acc[1][3] += a0.y * w.w;
            acc[2][0] += a0.z * w.x; acc[2][1] += a0.z * w.y; acc[2][2] += a0.z * w.z; acc[2][3] += a0.z * w.w;
            acc[3][0] += a0.w * w.x; acc[3][1] += a0.w * w.y; acc[3][2] += a0.w * w.z; acc[3][3] += a0.w * w.w;
            acc[4][0] += a1.x * w.x; acc[4][1] += a1.x * w.y; acc[4][2] += a1.x * w.z; acc[4][3] += a1.x * w.w;
            acc[5][0] += a1.y * w.x; acc[5][1] += a1.y * w.y; acc[5][2] += a1.y * w.z; acc[5][3] += a1.y * w.w;
            acc[6][0] += a1.z * w.x; acc[6][1] += a1.z * w.y; acc[6][2] += a1.z * w.z; acc[6][3] += a1.z * w.w;
            acc[7][0] += a1.w * w.x; acc[7][1] += a1.w * w.y; acc[7][2] += a1.w * w.z; acc[7][3] += a1.w * w.w;
        }
    }

    // epilogue: add bias, store (coalesced float4; reads of agg all done)
    const float4 bb = *(const float4*)(b_l + to * 4);
    #pragma unroll
    for (int n = 0; n < 8; ++n) {
        const int node = base + tm * 8 + n;
        if (node < n_nodes) {
            float4 r = make_float4(acc[n][0] + bb.x, acc[n][1] + bb.y,
                                   acc[n][2] + bb.z, acc[n][3] + bb.w);
            *(float4*)(out + (size_t)node * D + to * 4) = r;
        }
    }
}

// ---------------------------------------------------------------------------
extern "C" void kernel_launch(void* const* d_in, const int* in_sizes, int n_in,
                              void* d_out, int out_size, void* d_ws, size_t ws_size,
                              hipStream_t stream)
{
    const float* x         = (const float*)d_in[0];
    const float* edge_attr = (const float*)d_in[1];
    const float* W_e       = (const float*)d_in[2];
    const float* b_e       = (const float*)d_in[3];
    const float* W_l       = (const float*)d_in[4];
    const float* b_l       = (const float*)d_in[5];
    const float* W_r       = (const float*)d_in[6];
    const void*  edge_index= d_in[7];

    const int n_nodes = in_sizes[0] / D;
    const int n_edges = in_sizes[1] / ED;

    float* out = (float*)d_out;

    // workspace layout (bytes); offs gets n+1 entries (sentinel)
    const size_t n_align = ((size_t)n_nodes + 255) & ~(size_t)255;
    const int    NB      = (n_nodes + 255) / 256;       // scan blocks
    const size_t o_cnt   = 0;
    const size_t o_offs  = o_cnt  + n_align * 4;
    const size_t o_cur   = o_offs + n_align * 4 + 256;  // +256: sentinel room
    const size_t o_bsum  = o_cur  + n_align * 4;
    const size_t o_pair  = (o_bsum + (size_t)NB * 4 + 255) & ~(size_t)255;
    const size_t need    = o_pair + (size_t)n_edges * 8;

    if (need <= ws_size && NB <= 65536) {
        int*  cnt    = (int*)((char*)d_ws + o_cnt);
        int*  offs   = (int*)((char*)d_ws + o_offs);
        int*  cursor = (int*)((char*)d_ws + o_cur);
        int*  bsum   = (int*)((char*)d_ws + o_bsum);
        int2* pair   = (int2*)((char*)d_ws + o_pair);

        hipMemsetAsync(cnt, 0, n_align * 4, stream);

        count_kernel<<<2048, 256, 0, stream>>>(edge_index, cnt, n_edges);
        scan1_kernel<<<NB, 256, 0, stream>>>(cnt, offs, bsum, n_nodes);
        scan3_kernel<<<NB, 256, 0, stream>>>(offs, cursor, bsum, n_nodes, n_edges);
        scatter_kernel<<<2048, 256, 0, stream>>>(edge_index, cursor, pair, n_edges);
        reduce_kernel<<<2048, 256, 0, stream>>>(
            x, edge_attr, W_e, b_e, pair, offs, out, n_nodes);
    } else {
        // fallback: atomic scatter path
        float* cntf = (float*)((char*)d_ws + o_cnt);
        hipMemsetAsync(out, 0, (size_t)out_size * sizeof(float), stream);
        hipMemsetAsync(cntf, 0, (size_t)n_nodes * sizeof(float), stream);
        edge_scatter_kernel<<<4096, 256, 0, stream>>>(
            x, edge_attr, W_e, b_e, edge_index, out, cntf, n_edges);
        divide_kernel<<<(n_nodes * D + 255) / 256, 256, 0, stream>>>(out, cntf, n_nodes);
    }

    node_gemm_kernel<<<(n_nodes + BM - 1) / BM, 256, 0, stream>>>(
        x, out, W_l, b_l, W_r, out, n_nodes);
}